// Round 12
// baseline (54.092 us; speedup 1.0000x reference)
//
#include <hip/hip_runtime.h>
#include <math.h>

constexpr int T_LEN  = 8192;   // per-row length (== TREF)
constexpr int B_ROWS = 4096;
constexpr int NB     = 49;     // NBINS - 1 bins
constexpr int NC     = 32;     // histogram replicas
constexpr int HDIM   = 32;
constexpr int FBINS  = 8192;   // fine CDF resolution
constexpr int RPB    = 8;      // rows per block (main kernel)
constexpr int CHUNK  = 2048;   // floats per chunk (8 KB), 4 chunks per row
constexpr int RECW   = 52;     // 49 counts + lo + width + pad
constexpr float EPSF = 1e-10f;

constexpr int WS_CDF_OFF    = 8;
constexpr int WS_BINNED_OFF = 8208;

#define HP(i) ((i) + ((i) >> 5))

// counted vmcnt wait: oldest loads retired, deeper prefetch stays in flight
#define WAITV(N) do { asm volatile("s_waitcnt vmcnt(" #N ")" ::: "memory"); \
                      __builtin_amdgcn_sched_barrier(0); } while (0)

// LDS-only block sync: waits DS ops, leaves DMA loads in flight.
__device__ __forceinline__ void sync_lds() {
    asm volatile("s_waitcnt lgkmcnt(0)" ::: "memory");
    __builtin_amdgcn_s_barrier();
    __builtin_amdgcn_sched_barrier(0);
}

// -------- kernel 1 (1 block): ref min/max + fine histogram + CDF + scatter ----
__global__ __launch_bounds__(256)
void ref_cdf_kernel(const float* __restrict__ ref, float* __restrict__ wsf) {
    __shared__ float sv[FBINS];
    __shared__ int   hist[HP(FBINS)];
    __shared__ int   wsum[4];
    __shared__ float rmn4[4], rmx4[4];
    const int tid  = threadIdx.x;
    const int lane = tid & 63;
    const int wave = tid >> 6;

    const float4* r4 = (const float4*)ref;
    float4* sv4 = (float4*)sv;
    float mn = 3.0e38f, mx = -3.0e38f;
    #pragma unroll
    for (int i = 0; i < 8; ++i) {
        float4 v = r4[tid + i * 256];
        sv4[tid + i * 256] = v;
        mn = fminf(mn, fminf(fminf(v.x, v.y), fminf(v.z, v.w)));
        mx = fmaxf(mx, fmaxf(fmaxf(v.x, v.y), fmaxf(v.z, v.w)));
    }
    for (int i = tid; i < HP(FBINS); i += 256) hist[i] = 0;
    #pragma unroll
    for (int off = 32; off > 0; off >>= 1) {
        mn = fminf(mn, __shfl_xor(mn, off));
        mx = fmaxf(mx, __shfl_xor(mx, off));
    }
    if (lane == 0) { rmn4[wave] = mn; rmx4[wave] = mx; }
    __syncthreads();
    const float rmin = fminf(fminf(rmn4[0], rmn4[1]), fminf(rmn4[2], rmn4[3]));
    const float rmax = fmaxf(fmaxf(rmx4[0], rmx4[1]), fmaxf(rmx4[2], rmx4[3]));
    const float finv = (float)FBINS / (rmax - rmin);

    for (int i = tid; i < FBINS; i += 256) {
        int fb = min(max((int)((sv[i] - rmin) * finv), 0), FBINS - 1);
        atomicAdd(&hist[HP(fb)], 1);
    }
    __syncthreads();

    const int base = tid * 32;
    int s = 0;
    #pragma unroll
    for (int j = 0; j < 32; ++j) {
        int h = hist[HP(base + j)]; hist[HP(base + j)] = s; s += h;
    }
    const int own = s;
    int incl = s;
    #pragma unroll
    for (int off = 1; off < 64; off <<= 1) {
        int t = __shfl_up(incl, off);
        if (lane >= off) incl += t;
    }
    if (lane == 63) wsum[wave] = incl;
    __syncthreads();
    int woff = 0;
    #pragma unroll
    for (int w = 0; w < 4; ++w) if (w < wave) woff += wsum[w];
    const int add = woff + incl - own;
    #pragma unroll
    for (int j = 0; j < 32; ++j) hist[HP(base + j)] += add;
    __syncthreads();

    int* cdf = (int*)(wsf + WS_CDF_OFF);
    for (int i = tid; i < FBINS; i += 256) cdf[i] = hist[HP(i)];
    if (tid == 0) { cdf[FBINS] = T_LEN; wsf[0] = rmin; wsf[1] = rmax; }
    __syncthreads();

    float* binned = wsf + WS_BINNED_OFF;
    for (int i = tid; i < FBINS; i += 256) {
        float x = sv[i];
        int fb = min(max((int)((x - rmin) * finv), 0), FBINS - 1);
        int pos = atomicAdd(&hist[HP(fb)], 1);
        binned[pos] = x;
    }
}

// -------- kernel 2: deep-pipelined chunk ring -------------------------------
// 512 blocks x 8 rows; row = 4 x 8KB chunks; 8-slot LDS ring (= 2 rows).
// Steady state per wave: 8-16 chunk-DMAs outstanding (64-128 KB/CU) -- the
// memory system is never idle. Counted vmcnt waits consume chunks in FIFO
// order; bin pass re-reads the ring and re-issues each slot for row r+2.
__global__ __launch_bounds__(256, 2)
void kl_deep_kernel(const float* __restrict__ cur,
                    const float* __restrict__ wsf,
                    const float* __restrict__ w1,
                    const float* __restrict__ b1,
                    const float* __restrict__ w2,
                    const float* __restrict__ b2,
                    float* __restrict__ kl_out,
                    float* __restrict__ enc_out) {
    __shared__ float    ring[8][CHUNK];       // 64 KB
    __shared__ unsigned hq[NC * NB];          // 6272 B
    __shared__ float    scmn[4], scmx[4];
    __shared__ float    rec[RPB][RECW];

    const int tid  = threadIdx.x;
    const int lane = tid & 63;
    const int wave = tid >> 6;
    const int rbase = blockIdx.x * RPB;
    const float* src = cur + (size_t)rbase * T_LEN;
    const float rmin = wsf[0], rmax = wsf[1];

    // issue one chunk (2 DMAs/wave, 1 KB each); slot = (r&1)*4 + c
    auto issue_chunk = [&](int r, int c) {
        const int slot = ((r & 1) << 2) | c;
        const float* g = src + (size_t)r * T_LEN + c * CHUNK + wave * 512 + lane * 4;
        #pragma unroll
        for (int i = 0; i < 2; ++i) {
            __builtin_amdgcn_global_load_lds(
                (const __attribute__((address_space(1))) void*)(g + i * 256),
                (__attribute__((address_space(3))) void*)&ring[slot][wave * 512 + i * 256],
                16, 0, 0);
        }
    };
    // minmax-consume one staged chunk (own wave quarter)
    auto mmchunk = [&](int slot, float& mn, float& mx) {
        const float4* q = (const float4*)&ring[slot][wave * 512];
        float4 a0 = q[lane], a1 = q[lane + 64];
        mn = fminf(mn, fminf(fminf(a0.x, a0.y), fminf(a0.z, a0.w)));
        mx = fmaxf(mx, fmaxf(fmaxf(a0.x, a0.y), fmaxf(a0.z, a0.w)));
        mn = fminf(mn, fminf(fminf(a1.x, a1.y), fminf(a1.z, a1.w)));
        mx = fmaxf(mx, fmaxf(fmaxf(a1.x, a1.y), fmaxf(a1.z, a1.w)));
    };
    // finish a row: reduce minmax, bin all 4 chunks from the ring (re-issuing
    // each slot for row r+2), reduce replicas into rec[r], re-zero hq.
    auto finrow = [&](int r, float mn, float mx) {
        #pragma unroll
        for (int off = 32; off > 0; off >>= 1) {
            mn = fminf(mn, __shfl_xor(mn, off));
            mx = fmaxf(mx, __shfl_xor(mx, off));
        }
        if (lane == 0) { scmn[wave] = mn; scmx[wave] = mx; }
        sync_lds();                     // scmn/scmx + hq-zero visible
        const float lo = fminf(rmin,
            fminf(fminf(scmn[0], scmn[1]), fminf(scmn[2], scmn[3])));
        const float hi = fmaxf(rmax,
            fmaxf(fmaxf(scmx[0], scmx[1]), fmaxf(scmx[2], scmx[3])));
        const float width = (hi - lo) / (float)NB;
        const float winv = 1.0f / width, nlw = -lo * winv;

        unsigned* myq = hq + (tid & (NC - 1)) * NB;
        const int s0 = (r & 1) << 2;
        #pragma unroll
        for (int c = 0; c < 4; ++c) {
            const float4* q = (const float4*)&ring[s0 + c][wave * 512];
            float4 a0 = q[lane], a1 = q[lane + 64];
            int i0 = min((int)fmaf(a0.x, winv, nlw), NB - 1);
            int i1 = min((int)fmaf(a0.y, winv, nlw), NB - 1);
            int i2 = min((int)fmaf(a0.z, winv, nlw), NB - 1);
            int i3 = min((int)fmaf(a0.w, winv, nlw), NB - 1);
            int i4 = min((int)fmaf(a1.x, winv, nlw), NB - 1);
            int i5 = min((int)fmaf(a1.y, winv, nlw), NB - 1);
            int i6 = min((int)fmaf(a1.z, winv, nlw), NB - 1);
            int i7 = min((int)fmaf(a1.w, winv, nlw), NB - 1);
            atomicAdd(&myq[i0], 1u); atomicAdd(&myq[i1], 1u);
            atomicAdd(&myq[i2], 1u); atomicAdd(&myq[i3], 1u);
            if (r + 2 < RPB) issue_chunk(r + 2, c);   // slot consumed: refill
            atomicAdd(&myq[i4], 1u); atomicAdd(&myq[i5], 1u);
            atomicAdd(&myq[i6], 1u); atomicAdd(&myq[i7], 1u);
        }
        sync_lds();                     // all atomics done
        if (tid < NB) {
            unsigned sq = 0u;
            #pragma unroll
            for (int c = 0; c < NC; ++c) sq += hq[c * NB + tid];
            rec[r][tid] = (float)sq;
        }
        if (tid == NB)     rec[r][NB]     = lo;
        if (tid == NB + 1) rec[r][NB + 1] = width;
        sync_lds();                     // rec done before hq re-zeroed
        for (int i = tid; i < NC * NB; i += 256) hq[i] = 0u;
    };

    // prologue: rows 0 and 1 fully in flight (16 DMAs/wave), hq zeroed
    #pragma unroll
    for (int rc = 0; rc < 8; ++rc) issue_chunk(rc >> 2, rc & 3);
    for (int i = tid; i < NC * NB; i += 256) hq[i] = 0u;

    // rows 0..6: steady state, issued through (r+1,3) when entering row r
    for (int r = 0; r < RPB - 1; ++r) {
        const int s0 = (r & 1) << 2;
        float mn = 3.0e38f, mx = -3.0e38f;
        WAITV(14); mmchunk(s0 + 0, mn, mx);
        WAITV(12); mmchunk(s0 + 1, mn, mx);
        WAITV(10); mmchunk(s0 + 2, mn, mx);
        WAITV(8);  mmchunk(s0 + 3, mn, mx);
        finrow(r, mn, mx);
    }
    // row 7: nothing issued beyond it
    {
        const int s0 = (7 & 1) << 2;
        float mn = 3.0e38f, mx = -3.0e38f;
        WAITV(6); mmchunk(s0 + 0, mn, mx);
        WAITV(4); mmchunk(s0 + 1, mn, mx);
        WAITV(2); mmchunk(s0 + 2, mn, mx);
        WAITV(0); mmchunk(s0 + 3, mn, mx);
        finrow(7, mn, mx);
    }

    // ---- batched tails: wave w handles rows w and w+4 ----
    for (int rr = wave; rr < RPB; rr += 4) {
        const float lo = rec[rr][NB], width = rec[rr][NB + 1];
        const bool act = lane < NB;
        const float inv = 1.0f / ((float)T_LEN * width);
        float p = 0.0f, q = 0.0f;
        if (act) q = rec[rr][lane] * inv + EPSF;

        int C = T_LEN;
        if (lane < NB - 1) {
            const float kp1  = (float)(lane + 1);
            const float finv = (float)FBINS / (rmax - rmin);
            const int* cdf = (const int*)(wsf + WS_CDF_OFF);
            const float* binned = wsf + WS_BINNED_OFF;
            const float t = fmaf(width, kp1, lo);
            int fb = (int)floorf((t - rmin) * finv);
            int a  = min(max(fb - 2, 0), FBINS);
            int bb = min(max(fb + 3, 0), FBINS);
            int ia = cdf[a], ib = cdf[bb];
            C = ia;
            for (int i = ia; i < ib; i += 4) {
                float x0 = binned[i];
                float x1 = (i + 1 < ib) ? binned[i + 1] : 3.0e38f;
                float x2 = (i + 2 < ib) ? binned[i + 2] : 3.0e38f;
                float x3 = (i + 3 < ib) ? binned[i + 3] : 3.0e38f;
                C += ((x0 - lo) / width < kp1) ? 1 : 0;
                C += ((x1 - lo) / width < kp1) ? 1 : 0;
                C += ((x2 - lo) / width < kp1) ? 1 : 0;
                C += ((x3 - lo) / width < kp1) ? 1 : 0;
            }
        }
        int Cprev = __shfl_up(C, 1);
        if (lane == 0) Cprev = 0;
        if (act) p = (float)(C - Cprev) * inv + EPSF;

        float P = p, Q = q;
        #pragma unroll
        for (int off = 32; off > 0; off >>= 1) {
            P += __shfl_xor(P, off);
            Q += __shfl_xor(Q, off);
        }
        float term = 0.0f;
        if (act) {
            const float pn = p / P;
            const float qn = q / Q;
            term = pn * logf(pn / qn);
        }
        #pragma unroll
        for (int off = 32; off > 0; off >>= 1) term += __shfl_xor(term, off);
        if (lane == 0) kl_out[rbase + rr] = term;

        if (lane < HDIM) {
            float acc = b2[lane];
            #pragma unroll
            for (int t2 = 0; t2 < HDIM; ++t2) {
                float h = fmaxf(fmaf(term, w1[t2], b1[t2]), 0.0f);
                acc = fmaf(h, w2[lane * HDIM + t2], acc);
            }
            enc_out[(size_t)(rbase + rr) * HDIM + lane] = acc;
        }
    }
}

extern "C" void kernel_launch(void* const* d_in, const int* in_sizes, int n_in,
                              void* d_out, int out_size, void* d_ws, size_t ws_size,
                              hipStream_t stream) {
    const float* cur = (const float*)d_in[0];
    const float* ref = (const float*)d_in[1];
    const float* w1  = (const float*)d_in[2];
    const float* b1  = (const float*)d_in[3];
    const float* w2  = (const float*)d_in[4];
    const float* b2  = (const float*)d_in[5];
    float* out = (float*)d_out;           // [0, B) = kl ; [B, B + B*H) = encoded
    float* wsf = (float*)d_ws;

    ref_cdf_kernel<<<1, 256, 0, stream>>>(ref, wsf);
    kl_deep_kernel<<<B_ROWS / RPB, 256, 0, stream>>>(
        cur, wsf, w1, b1, w2, b2, out, out + B_ROWS);
}

// Round 13
// 44.307 us; speedup vs baseline: 1.2208x; 1.2208x over previous
//
#include <hip/hip_runtime.h>
#include <math.h>

constexpr int T_LEN  = 8192;   // per-row length (== TREF)
constexpr int B_ROWS = 4096;
constexpr int NB     = 49;     // NBINS - 1 bins
constexpr int NR     = 64;     // histogram replicas: one per lane
constexpr int RSTR   = 51;     // replica stride (odd, co-prime-ish with 32)
constexpr int HDIM   = 32;
constexpr int FBINS  = 8192;   // fine CDF resolution
constexpr float EPSF = 1e-10f;

// ws layout (float units): [0]=rmin [1]=rmax ; int cdf[FBINS+1] at +8 ;
// float binned[T_LEN] (counting-scattered ref) at +8208
constexpr int WS_CDF_OFF    = 8;
constexpr int WS_BINNED_OFF = 8208;

#define HP(i) ((i) + ((i) >> 5))

__device__ __forceinline__ void lds_fence() {
    asm volatile("s_waitcnt lgkmcnt(0)" ::: "memory");
    __builtin_amdgcn_sched_barrier(0);
}

// -------- kernel 1 (1 block): ref min/max + fine histogram + CDF + scatter ----
__global__ __launch_bounds__(256)
void ref_cdf_kernel(const float* __restrict__ ref, float* __restrict__ wsf) {
    __shared__ float sv[FBINS];
    __shared__ int   hist[HP(FBINS)];
    __shared__ int   wsum[4];
    __shared__ float rmn4[4], rmx4[4];
    const int tid  = threadIdx.x;
    const int lane = tid & 63;
    const int wave = tid >> 6;

    const float4* r4 = (const float4*)ref;
    float4* sv4 = (float4*)sv;
    float mn = 3.0e38f, mx = -3.0e38f;
    #pragma unroll
    for (int i = 0; i < 8; ++i) {
        float4 v = r4[tid + i * 256];
        sv4[tid + i * 256] = v;
        mn = fminf(mn, fminf(fminf(v.x, v.y), fminf(v.z, v.w)));
        mx = fmaxf(mx, fmaxf(fmaxf(v.x, v.y), fmaxf(v.z, v.w)));
    }
    for (int i = tid; i < HP(FBINS); i += 256) hist[i] = 0;
    #pragma unroll
    for (int off = 32; off > 0; off >>= 1) {
        mn = fminf(mn, __shfl_xor(mn, off));
        mx = fmaxf(mx, __shfl_xor(mx, off));
    }
    if (lane == 0) { rmn4[wave] = mn; rmx4[wave] = mx; }
    __syncthreads();
    const float rmin = fminf(fminf(rmn4[0], rmn4[1]), fminf(rmn4[2], rmn4[3]));
    const float rmax = fmaxf(fmaxf(rmx4[0], rmx4[1]), fmaxf(rmx4[2], rmx4[3]));
    const float finv = (float)FBINS / (rmax - rmin);

    for (int i = tid; i < FBINS; i += 256) {
        int fb = min(max((int)((sv[i] - rmin) * finv), 0), FBINS - 1);
        atomicAdd(&hist[HP(fb)], 1);
    }
    __syncthreads();

    const int base = tid * 32;
    int s = 0;
    #pragma unroll
    for (int j = 0; j < 32; ++j) {
        int h = hist[HP(base + j)]; hist[HP(base + j)] = s; s += h;
    }
    const int own = s;
    int incl = s;
    #pragma unroll
    for (int off = 1; off < 64; off <<= 1) {
        int t = __shfl_up(incl, off);
        if (lane >= off) incl += t;
    }
    if (lane == 63) wsum[wave] = incl;
    __syncthreads();
    int woff = 0;
    #pragma unroll
    for (int w = 0; w < 4; ++w) if (w < wave) woff += wsum[w];
    const int add = woff + incl - own;
    #pragma unroll
    for (int j = 0; j < 32; ++j) hist[HP(base + j)] += add;
    __syncthreads();

    int* cdf = (int*)(wsf + WS_CDF_OFF);
    for (int i = tid; i < FBINS; i += 256) cdf[i] = hist[HP(i)];
    if (tid == 0) { cdf[FBINS] = T_LEN; wsf[0] = rmin; wsf[1] = rmax; }
    __syncthreads();

    float* binned = wsf + WS_BINNED_OFF;
    for (int i = tid; i < FBINS; i += 256) {
        float x = sv[i];
        int fb = min(max((int)((x - rmin) * finv), 0), FBINS - 1);
        int pos = atomicAdd(&hist[HP(fb)], 1);
        binned[pos] = x;
    }
}

// -------- kernel 2: one ROW per 64-thread block; lane-private histograms ----
// Row in 32 x float4 registers. Histogram: 64 replicas (one per lane,
// stride 51) -> zero same-address RMW serialization, ~2 lanes/bank (free).
// Tail (CDF-window ref counts + KL + MLP) inline on the same wave.
__global__ __launch_bounds__(64, 3)
void kl_wave_kernel(const float* __restrict__ cur,
                    const float* __restrict__ wsf,
                    const float* __restrict__ w1,
                    const float* __restrict__ b1,
                    const float* __restrict__ w2,
                    const float* __restrict__ b2,
                    float* __restrict__ kl_out,
                    float* __restrict__ enc_out) {
    __shared__ unsigned hq[NR * RSTR];        // 13056 B

    const int lane = threadIdx.x;             // 0..63
    const int b    = blockIdx.x;
    const float4* src = (const float4*)(cur + (size_t)b * T_LEN);

    // issue the entire row: 32 independent 16B loads per lane
    float4 v[32];
    #pragma unroll
    for (int i = 0; i < 32; ++i) v[i] = src[lane + i * 64];

    // zero all replicas while loads are in flight (lane-strided: conflict-free)
    #pragma unroll
    for (int i = 0; i < NR * RSTR / 64; ++i) hq[lane + i * 64] = 0u;
    const float rmin = wsf[0], rmax = wsf[1];

    // ---- min/max ----
    float mn = 3.0e38f, mx = -3.0e38f;
    #pragma unroll
    for (int i = 0; i < 32; ++i) {
        mn = fminf(mn, fminf(fminf(v[i].x, v[i].y), fminf(v[i].z, v[i].w)));
        mx = fmaxf(mx, fmaxf(fmaxf(v[i].x, v[i].y), fmaxf(v[i].z, v[i].w)));
    }
    #pragma unroll
    for (int off = 32; off > 0; off >>= 1) {
        mn = fminf(mn, __shfl_xor(mn, off));
        mx = fmaxf(mx, __shfl_xor(mx, off));
    }
    const float lo = fminf(rmin, mn);
    const float hi = fmaxf(rmax, mx);
    const float width = (hi - lo) / (float)NB;
    const float winv = 1.0f / width, nlw = -lo * winv;

    // ---- histogram into the lane-private replica ----
    unsigned* myq = hq + lane * RSTR;          // per-lane base: no same-address
    #pragma unroll
    for (int i = 0; i < 32; ++i) {
        int i0 = min((int)fmaf(v[i].x, winv, nlw), NB - 1);
        int i1 = min((int)fmaf(v[i].y, winv, nlw), NB - 1);
        int i2 = min((int)fmaf(v[i].z, winv, nlw), NB - 1);
        int i3 = min((int)fmaf(v[i].w, winv, nlw), NB - 1);
        atomicAdd(&myq[i0], 1u); atomicAdd(&myq[i1], 1u);
        atomicAdd(&myq[i2], 1u); atomicAdd(&myq[i3], 1u);
    }
    lds_fence();                               // wave's atomics complete

    // ---- tail: reduce replicas, ref counts via fine-CDF window, KL, MLP ----
    const bool act = lane < NB;
    const float inv = 1.0f / ((float)T_LEN * width);
    float p = 0.0f, q = 0.0f;
    if (act) {
        unsigned sq = 0u;
        #pragma unroll
        for (int r = 0; r < NR; ++r) sq += hq[r * RSTR + lane];  // lanes consecutive
        q = (float)sq * inv + EPSF;
    }
    int C = T_LEN;
    if (lane < NB - 1) {
        const float kp1  = (float)(lane + 1);
        const float finv = (float)FBINS / (rmax - rmin);
        const int* cdf = (const int*)(wsf + WS_CDF_OFF);
        const float* binned = wsf + WS_BINNED_OFF;
        const float t = fmaf(width, kp1, lo);
        int fb = (int)floorf((t - rmin) * finv);
        int a  = min(max(fb - 2, 0), FBINS);
        int bb = min(max(fb + 3, 0), FBINS);
        int ia = cdf[a], ib = cdf[bb];
        C = ia;
        for (int i = ia; i < ib; i += 4) {
            float x0 = binned[i];
            float x1 = (i + 1 < ib) ? binned[i + 1] : 3.0e38f;
            float x2 = (i + 2 < ib) ? binned[i + 2] : 3.0e38f;
            float x3 = (i + 3 < ib) ? binned[i + 3] : 3.0e38f;
            C += ((x0 - lo) / width < kp1) ? 1 : 0;
            C += ((x1 - lo) / width < kp1) ? 1 : 0;
            C += ((x2 - lo) / width < kp1) ? 1 : 0;
            C += ((x3 - lo) / width < kp1) ? 1 : 0;
        }
    }
    int Cprev = __shfl_up(C, 1);
    if (lane == 0) Cprev = 0;
    if (act) p = (float)(C - Cprev) * inv + EPSF;

    float P = p, Q = q;
    #pragma unroll
    for (int off = 32; off > 0; off >>= 1) {
        P += __shfl_xor(P, off);
        Q += __shfl_xor(Q, off);
    }
    float term = 0.0f;
    if (act) {
        const float pn = p / P;
        const float qn = q / Q;
        term = pn * logf(pn / qn);
    }
    #pragma unroll
    for (int off = 32; off > 0; off >>= 1) term += __shfl_xor(term, off);
    if (lane == 0) kl_out[b] = term;

    if (lane < HDIM) {
        float acc = b2[lane];
        #pragma unroll
        for (int t2 = 0; t2 < HDIM; ++t2) {
            float h = fmaxf(fmaf(term, w1[t2], b1[t2]), 0.0f);
            acc = fmaf(h, w2[lane * HDIM + t2], acc);
        }
        enc_out[(size_t)b * HDIM + lane] = acc;
    }
}

extern "C" void kernel_launch(void* const* d_in, const int* in_sizes, int n_in,
                              void* d_out, int out_size, void* d_ws, size_t ws_size,
                              hipStream_t stream) {
    const float* cur = (const float*)d_in[0];
    const float* ref = (const float*)d_in[1];
    const float* w1  = (const float*)d_in[2];
    const float* b1  = (const float*)d_in[3];
    const float* w2  = (const float*)d_in[4];
    const float* b2  = (const float*)d_in[5];
    float* out = (float*)d_out;           // [0, B) = kl ; [B, B + B*H) = encoded
    float* wsf = (float*)d_ws;

    ref_cdf_kernel<<<1, 256, 0, stream>>>(ref, wsf);
    kl_wave_kernel<<<B_ROWS, 64, 0, stream>>>(
        cur, wsf, w1, b1, w2, b2, out, out + B_ROWS);
}